// Round 5
// baseline (153.766 us; speedup 1.0000x reference)
//
#include <hip/hip_runtime.h>

#define B_    2
#define N1_   256
#define N2_   256
#define DIN_  1024
#define DRED_ 512
#define DREP_ 1024

typedef unsigned short ushort_t;
typedef float f32x4 __attribute__((ext_vector_type(4)));
typedef short bf16x8 __attribute__((ext_vector_type(8)));

__device__ __forceinline__ ushort_t f2bf(float x) {
    unsigned u = __builtin_bit_cast(unsigned, x);
    unsigned r = (u + 0x7fffu + ((u >> 16) & 1u)) >> 16;   // RNE
    return (ushort_t)r;
}
__device__ __forceinline__ float bf2f(ushort_t h) {
    unsigned u = ((unsigned)h) << 16;
    return __builtin_bit_cast(float, u);
}
__device__ __forceinline__ void mfma16(f32x4& acc, bf16x8 a, bf16x8 b) {
    acc = __builtin_amdgcn_mfma_f32_16x16x32_bf16(a, b, acc, 0, 0, 0);
}

// One launch: transpose+split BOTH weights.
// blockIdx.x < 8  -> W_red  [1024][512]  -> Wrth/Wrtl [512][1024]
// else            -> W_repr [1024][1024] -> Wpth/Wptl [1024][1024]
__global__ __launch_bounds__(256) void prep_weights(
    const float* __restrict__ W_red, const float* __restrict__ W_repr,
    ushort_t* __restrict__ Wrth, ushort_t* __restrict__ Wrtl,
    ushort_t* __restrict__ Wpth, ushort_t* __restrict__ Wptl)
{
    int bx = blockIdx.x;
    const float* W; ushort_t *Th, *Tl; int N;
    if (bx < 8) { W = W_red;  Th = Wrth; Tl = Wrtl; N = DRED_; }
    else        { bx -= 8; W = W_repr; Th = Wpth; Tl = Wptl; N = DREP_; }
    const int K = 1024;

    __shared__ float T[64][65];
    const int tid = threadIdx.x;
    const int n0 = bx * 64;
    const int k0 = blockIdx.y * 64;
    #pragma unroll
    for (int p = 0; p < 4; ++p) {
        int r = (tid >> 4) + p * 16;
        int c = (tid & 15) * 4;
        float4 v = *reinterpret_cast<const float4*>(&W[(size_t)(k0 + r) * N + n0 + c]);
        T[r][c] = v.x; T[r][c + 1] = v.y; T[r][c + 2] = v.z; T[r][c + 3] = v.w;
    }
    __syncthreads();
    #pragma unroll
    for (int p = 0; p < 4; ++p) {
        int rn = (tid >> 4) + p * 16;
        int ck = (tid & 15) * 4;
        ushort_t hh[4], ll[4];
        #pragma unroll
        for (int j = 0; j < 4; ++j) {
            float v = T[ck + j][rn];
            hh[j] = f2bf(v);
            ll[j] = f2bf(v - bf2f(hh[j]));
        }
        *reinterpret_cast<ushort4*>(&Th[(size_t)(n0 + rn) * K + k0 + ck]) =
            ushort4{hh[0], hh[1], hh[2], hh[3]};
        *reinterpret_cast<ushort4*>(&Tl[(size_t)(n0 + rn) * K + k0 + ck]) =
            ushort4{ll[0], ll[1], ll[2], ll[3]};
    }
}

// Split-bf16 MFMA GEMM, dual tenant. Tile BM=32, BN=64, BK=64; 4 waves.
// MODE 0: A fp32 (split in staging); C = relu(A@B+bias) -> hi/lo bf16.
// MODE 1: A hi/lo bf16; C = A@B (+bias if non-null) -> fp32.
// B pre-transposed/split [N][ldb]; bOff selects k-slice.
template<int MODE>
__global__ __launch_bounds__(256) void gemm_split(
    const float* __restrict__ Af0, const float* __restrict__ Af1,
    const ushort_t* __restrict__ Ah0, const ushort_t* __restrict__ Al0,
    const ushort_t* __restrict__ Ah1, const ushort_t* __restrict__ Al1,
    const ushort_t* __restrict__ Bh, const ushort_t* __restrict__ Bl,
    int bOff0, int bOff1,
    const float* __restrict__ bias0, const float* __restrict__ bias1,
    ushort_t* __restrict__ Ch0, ushort_t* __restrict__ Cl0,
    ushort_t* __restrict__ Ch1, ushort_t* __restrict__ Cl1,
    float* __restrict__ Cf0, float* __restrict__ Cf1,
    int M, int N, int K, int lda, int ldb)
{
    __shared__ ushort_t Ash[32][72];
    __shared__ ushort_t Asl[32][72];
    __shared__ ushort_t Bsh[64][72];
    __shared__ ushort_t Bsl[64][72];

    const int tid = threadIdx.x;
    const int z  = blockIdx.z;
    const int m0 = blockIdx.y * 32;
    const int n0 = blockIdx.x * 64;

    const float*    Af   = z ? Af1 : Af0;
    const ushort_t* Ah   = z ? Ah1 : Ah0;
    const ushort_t* Al   = z ? Al1 : Al0;
    const int       bOff = z ? bOff1 : bOff0;
    const float*    bias = z ? bias1 : bias0;

    const int lane = tid & 63;
    const int w    = tid >> 6;
    const int m_w  = (w >> 1) * 16;
    const int n_w  = (w & 1) * 32;
    const int lrow = lane & 15;
    const int lkg  = (lane >> 4) * 8;

    const int ar  = tid >> 3;          // 0..31
    const int ac8 = (tid & 7) * 8;     // 8-elem column group
    const int br  = tid >> 2;          // 0..63
    const int bc  = (tid & 3) * 16;    // 16-ushort group? no: use 2 passes of 8

    f32x4 acc[2] = {};

    for (int k0 = 0; k0 < K; k0 += 64) {
        // ---- stage A (32 rows x 64 k) ----
        if (MODE == 0) {
            float4 v0 = *reinterpret_cast<const float4*>(&Af[(size_t)(m0 + ar) * lda + k0 + ac8]);
            float4 v1 = *reinterpret_cast<const float4*>(&Af[(size_t)(m0 + ar) * lda + k0 + ac8 + 4]);
            float vv[8] = {v0.x, v0.y, v0.z, v0.w, v1.x, v1.y, v1.z, v1.w};
            ushort_t hh[8], ll[8];
            #pragma unroll
            for (int j = 0; j < 8; ++j) {
                hh[j] = f2bf(vv[j]);
                ll[j] = f2bf(vv[j] - bf2f(hh[j]));
            }
            *reinterpret_cast<ushort4*>(&Ash[ar][ac8])     = ushort4{hh[0], hh[1], hh[2], hh[3]};
            *reinterpret_cast<ushort4*>(&Ash[ar][ac8 + 4]) = ushort4{hh[4], hh[5], hh[6], hh[7]};
            *reinterpret_cast<ushort4*>(&Asl[ar][ac8])     = ushort4{ll[0], ll[1], ll[2], ll[3]};
            *reinterpret_cast<ushort4*>(&Asl[ar][ac8 + 4]) = ushort4{ll[4], ll[5], ll[6], ll[7]};
        } else {
            *reinterpret_cast<uint4*>(&Ash[ar][ac8]) =
                *reinterpret_cast<const uint4*>(&Ah[(size_t)(m0 + ar) * lda + k0 + ac8]);
            *reinterpret_cast<uint4*>(&Asl[ar][ac8]) =
                *reinterpret_cast<const uint4*>(&Al[(size_t)(m0 + ar) * lda + k0 + ac8]);
        }
        // ---- stage B (64 n-rows x 64 k), pre-transposed/split ----
        #pragma unroll
        for (int p = 0; p < 2; ++p) {
            int r = (tid >> 3) + p * 32;
            int c = (tid & 7) * 8;
            *reinterpret_cast<uint4*>(&Bsh[r][c]) =
                *reinterpret_cast<const uint4*>(&Bh[(size_t)(n0 + r) * ldb + bOff + k0 + c]);
            *reinterpret_cast<uint4*>(&Bsl[r][c]) =
                *reinterpret_cast<const uint4*>(&Bl[(size_t)(n0 + r) * ldb + bOff + k0 + c]);
        }
        __syncthreads();

        #pragma unroll
        for (int s = 0; s < 2; ++s) {
            const int kk = s * 32 + lkg;
            bf16x8 ah = *reinterpret_cast<const bf16x8*>(&Ash[m_w + lrow][kk]);
            bf16x8 al = *reinterpret_cast<const bf16x8*>(&Asl[m_w + lrow][kk]);
            #pragma unroll
            for (int ni = 0; ni < 2; ++ni) {
                bf16x8 bh = *reinterpret_cast<const bf16x8*>(&Bsh[n_w + ni * 16 + lrow][kk]);
                bf16x8 bl = *reinterpret_cast<const bf16x8*>(&Bsl[n_w + ni * 16 + lrow][kk]);
                mfma16(acc[ni], ah, bh);
                mfma16(acc[ni], ah, bl);
                mfma16(acc[ni], al, bh);
            }
        }
        __syncthreads();
    }

    ushort_t* Ch = z ? Ch1 : Ch0;
    ushort_t* Cl = z ? Cl1 : Cl0;
    float*    Cf = z ? Cf1 : Cf0;

    #pragma unroll
    for (int ni = 0; ni < 2; ++ni)
        #pragma unroll
        for (int j = 0; j < 4; ++j) {
            const int m = m0 + m_w + (lane >> 4) * 4 + j;
            const int n = n0 + n_w + ni * 16 + (lane & 15);
            float v = acc[ni][j];
            if (MODE == 0) {
                v += bias[n];
                v = fmaxf(v, 0.f);
                ushort_t h = f2bf(v);
                Ch[(size_t)m * N + n] = h;
                Cl[(size_t)m * N + n] = f2bf(v - bf2f(h));
            } else {
                if (bias) v += bias[n];
                Cf[(size_t)m * N + n] = v;
            }
        }
}

// Linear fill-style broadcast: idx decodes [b][n][m][d]; one f32x4/thread/iter.
__global__ __launch_bounds__(256) void bcast_relu(
    const f32x4* __restrict__ A1, const f32x4* __restrict__ A2,
    f32x4* __restrict__ out)
{
    const unsigned total  = (unsigned)B_ * N1_ * N2_ * (DREP_ / 4);  // 33554432
    const unsigned stride = gridDim.x * 256u;
    unsigned idx = blockIdx.x * 256u + threadIdx.x;

    for (; idx < total; idx += stride) {
        const unsigned d  = idx & 255u;
        const unsigned m  = (idx >> 8) & 255u;
        const unsigned bn = idx >> 16;           // b*256 + n
        const unsigned b  = bn >> 8;
        const f32x4 a1 = A1[((size_t)bn << 8) | d];
        const f32x4 a2 = A2[(((size_t)((b << 8) | m)) << 8) | d];
        f32x4 v;
        v.x = fmaxf(a1.x + a2.x, 0.f);
        v.y = fmaxf(a1.y + a2.y, 0.f);
        v.z = fmaxf(a1.z + a2.z, 0.f);
        v.w = fmaxf(a1.w + a2.w, 0.f);
        out[idx] = v;
    }
}

extern "C" void kernel_launch(void* const* d_in, const int* in_sizes, int n_in,
                              void* d_out, int out_size, void* d_ws, size_t ws_size,
                              hipStream_t stream) {
    const float* span1  = (const float*)d_in[0];
    const float* span2  = (const float*)d_in[1];
    const float* W_red  = (const float*)d_in[2];
    const float* b_red  = (const float*)d_in[3];
    const float* W_repr = (const float*)d_in[4];
    const float* b_repr = (const float*)d_in[5];
    float* out = (float*)d_out;

    // workspace carve (~12 MB)
    float* A1 = (float*)d_ws;                       // 512*1024 f32
    float* A2 = A1 + 512 * 1024;
    ushort_t* p = (ushort_t*)(A2 + 512 * 1024);
    ushort_t* r1h = p;  p += 512 * 512;
    ushort_t* r1l = p;  p += 512 * 512;
    ushort_t* r2h = p;  p += 512 * 512;
    ushort_t* r2l = p;  p += 512 * 512;
    ushort_t* Wrth = p; p += 512 * 1024;            // W_red^T  [512][1024]
    ushort_t* Wrtl = p; p += 512 * 1024;
    ushort_t* Wpth = p; p += 1024 * 1024;           // W_repr^T [1024][1024]
    ushort_t* Wptl = p; p += 1024 * 1024;

    // one launch: transpose+split both weights
    prep_weights<<<dim3(24, 16), 256, 0, stream>>>(
        W_red, W_repr, Wrth, Wrtl, Wpth, Wptl);

    const int M = B_ * N1_;   // 512

    // stage 1: r{1,2} = relu(span{1,2} @ W_red + b_red) -> hi/lo bf16
    gemm_split<0><<<dim3(DRED_ / 64, M / 32, 2), 256, 0, stream>>>(
        span1, span2, nullptr, nullptr, nullptr, nullptr,
        Wrth, Wrtl, 0, 0, b_red, b_red,
        r1h, r1l, r2h, r2l, nullptr, nullptr,
        M, DRED_, DIN_, DIN_, DIN_);

    // stage 2: A1 = r1 @ Wa + b_repr ; A2 = r2 @ Wb
    gemm_split<1><<<dim3(DREP_ / 64, M / 32, 2), 256, 0, stream>>>(
        nullptr, nullptr, r1h, r1l, r2h, r2l,
        Wpth, Wptl, 0, DRED_, b_repr, nullptr,
        nullptr, nullptr, nullptr, nullptr, A1, A2,
        M, DREP_, DRED_, DRED_, 2 * DRED_);

    // stage 3: fill-style linear broadcast + relu
    bcast_relu<<<dim3(4096), 256, 0, stream>>>(
        (const f32x4*)A1, (const f32x4*)A2, (f32x4*)out);
}

// Round 6
// 139.325 us; speedup vs baseline: 1.1037x; 1.1037x over previous
//
#include <hip/hip_runtime.h>

#define B_    2
#define N1_   256
#define N2_   256
#define DIN_  1024
#define DRED_ 512
#define DREP_ 1024

typedef unsigned short ushort_t;
typedef float f32x4 __attribute__((ext_vector_type(4)));
typedef short bf16x8 __attribute__((ext_vector_type(8)));

__device__ __forceinline__ ushort_t f2bf(float x) {
    unsigned u = __builtin_bit_cast(unsigned, x);
    unsigned r = (u + 0x7fffu + ((u >> 16) & 1u)) >> 16;   // RNE
    return (ushort_t)r;
}
__device__ __forceinline__ float bf2f(ushort_t h) {
    unsigned u = ((unsigned)h) << 16;
    return __builtin_bit_cast(float, u);
}
__device__ __forceinline__ void mfma16(f32x4& acc, bf16x8 a, bf16x8 b) {
    acc = __builtin_amdgcn_mfma_f32_16x16x32_bf16(a, b, acc, 0, 0, 0);
}

// One launch: transpose+split BOTH weights.
// blockIdx.x < 8  -> W_red  [1024][512]  -> Wrth/Wrtl [512][1024]
// else            -> W_repr [1024][1024] -> Wpth/Wptl [1024][1024]
__global__ __launch_bounds__(256) void prep_weights(
    const float* __restrict__ W_red, const float* __restrict__ W_repr,
    ushort_t* __restrict__ Wrth, ushort_t* __restrict__ Wrtl,
    ushort_t* __restrict__ Wpth, ushort_t* __restrict__ Wptl)
{
    int bx = blockIdx.x;
    const float* W; ushort_t *Th, *Tl; int N;
    if (bx < 8) { W = W_red;  Th = Wrth; Tl = Wrtl; N = DRED_; }
    else        { bx -= 8; W = W_repr; Th = Wpth; Tl = Wptl; N = DREP_; }
    const int K = 1024;

    __shared__ float T[64][65];
    const int tid = threadIdx.x;
    const int n0 = bx * 64;
    const int k0 = blockIdx.y * 64;
    #pragma unroll
    for (int p = 0; p < 4; ++p) {
        int r = (tid >> 4) + p * 16;
        int c = (tid & 15) * 4;
        float4 v = *reinterpret_cast<const float4*>(&W[(size_t)(k0 + r) * N + n0 + c]);
        T[r][c] = v.x; T[r][c + 1] = v.y; T[r][c + 2] = v.z; T[r][c + 3] = v.w;
    }
    __syncthreads();
    #pragma unroll
    for (int p = 0; p < 4; ++p) {
        int rn = (tid >> 4) + p * 16;
        int ck = (tid & 15) * 4;
        ushort_t hh[4], ll[4];
        #pragma unroll
        for (int j = 0; j < 4; ++j) {
            float v = T[ck + j][rn];
            hh[j] = f2bf(v);
            ll[j] = f2bf(v - bf2f(hh[j]));
        }
        *reinterpret_cast<ushort4*>(&Th[(size_t)(n0 + rn) * K + k0 + ck]) =
            ushort4{hh[0], hh[1], hh[2], hh[3]};
        *reinterpret_cast<ushort4*>(&Tl[(size_t)(n0 + rn) * K + k0 + ck]) =
            ushort4{ll[0], ll[1], ll[2], ll[3]};
    }
}

// Split-bf16 MFMA GEMM, dual tenant. Tile BM=16, BN=64, BK=64; 4 waves,
// each wave owns one 16x16 output fragment column (n_w = w*16).
// MODE 0: A fp32 (split in staging); C = relu(A@B+bias) -> hi/lo bf16.
// MODE 1: A hi/lo bf16; C = A@B (+bias if non-null) -> fp32.
// B pre-transposed/split [N][ldb]; bOff selects k-slice.
template<int MODE>
__global__ __launch_bounds__(256) void gemm_split(
    const float* __restrict__ Af0, const float* __restrict__ Af1,
    const ushort_t* __restrict__ Ah0, const ushort_t* __restrict__ Al0,
    const ushort_t* __restrict__ Ah1, const ushort_t* __restrict__ Al1,
    const ushort_t* __restrict__ Bh, const ushort_t* __restrict__ Bl,
    int bOff0, int bOff1,
    const float* __restrict__ bias0, const float* __restrict__ bias1,
    ushort_t* __restrict__ Ch0, ushort_t* __restrict__ Cl0,
    ushort_t* __restrict__ Ch1, ushort_t* __restrict__ Cl1,
    float* __restrict__ Cf0, float* __restrict__ Cf1,
    int M, int N, int K, int lda, int ldb)
{
    __shared__ ushort_t Ash[16][72];
    __shared__ ushort_t Asl[16][72];
    __shared__ ushort_t Bsh[64][72];
    __shared__ ushort_t Bsl[64][72];

    const int tid = threadIdx.x;
    const int z  = blockIdx.z;
    const int m0 = blockIdx.y * 16;
    const int n0 = blockIdx.x * 64;

    const float*    Af   = z ? Af1 : Af0;
    const ushort_t* Ah   = z ? Ah1 : Ah0;
    const ushort_t* Al   = z ? Al1 : Al0;
    const int       bOff = z ? bOff1 : bOff0;
    const float*    bias = z ? bias1 : bias0;

    const int lane = tid & 63;
    const int w    = tid >> 6;
    const int n_w  = w * 16;
    const int lrow = lane & 15;
    const int lkg  = (lane >> 4) * 8;

    // staging indices: A tile 16 rows x 64 k
    const int ar  = tid >> 4;          // 0..15
    const int ac4 = (tid & 15) * 4;    // 4-elem col group

    f32x4 acc = {};

    for (int k0 = 0; k0 < K; k0 += 64) {
        // ---- stage A (16 x 64) ----
        if (MODE == 0) {
            float4 v = *reinterpret_cast<const float4*>(&Af[(size_t)(m0 + ar) * lda + k0 + ac4]);
            float vv[4] = {v.x, v.y, v.z, v.w};
            ushort_t hh[4], ll[4];
            #pragma unroll
            for (int j = 0; j < 4; ++j) {
                hh[j] = f2bf(vv[j]);
                ll[j] = f2bf(vv[j] - bf2f(hh[j]));
            }
            *reinterpret_cast<ushort4*>(&Ash[ar][ac4]) = ushort4{hh[0], hh[1], hh[2], hh[3]};
            *reinterpret_cast<ushort4*>(&Asl[ar][ac4]) = ushort4{ll[0], ll[1], ll[2], ll[3]};
        } else {
            *reinterpret_cast<ushort4*>(&Ash[ar][ac4]) =
                *reinterpret_cast<const ushort4*>(&Ah[(size_t)(m0 + ar) * lda + k0 + ac4]);
            *reinterpret_cast<ushort4*>(&Asl[ar][ac4]) =
                *reinterpret_cast<const ushort4*>(&Al[(size_t)(m0 + ar) * lda + k0 + ac4]);
        }
        // ---- stage B (64 n-rows x 64 k), pre-transposed/split ----
        #pragma unroll
        for (int p = 0; p < 2; ++p) {
            int r = (tid >> 3) + p * 32;
            int c = (tid & 7) * 8;
            *reinterpret_cast<uint4*>(&Bsh[r][c]) =
                *reinterpret_cast<const uint4*>(&Bh[(size_t)(n0 + r) * ldb + bOff + k0 + c]);
            *reinterpret_cast<uint4*>(&Bsl[r][c]) =
                *reinterpret_cast<const uint4*>(&Bl[(size_t)(n0 + r) * ldb + bOff + k0 + c]);
        }
        __syncthreads();

        #pragma unroll
        for (int s = 0; s < 2; ++s) {
            const int kk = s * 32 + lkg;
            bf16x8 ah = *reinterpret_cast<const bf16x8*>(&Ash[lrow][kk]);
            bf16x8 al = *reinterpret_cast<const bf16x8*>(&Asl[lrow][kk]);
            bf16x8 bh = *reinterpret_cast<const bf16x8*>(&Bsh[n_w + lrow][kk]);
            bf16x8 bl = *reinterpret_cast<const bf16x8*>(&Bsl[n_w + lrow][kk]);
            mfma16(acc, ah, bh);
            mfma16(acc, ah, bl);
            mfma16(acc, al, bh);
        }
        __syncthreads();
    }

    ushort_t* Ch = z ? Ch1 : Ch0;
    ushort_t* Cl = z ? Cl1 : Cl0;
    float*    Cf = z ? Cf1 : Cf0;

    #pragma unroll
    for (int j = 0; j < 4; ++j) {
        const int m = m0 + (lane >> 4) * 4 + j;
        const int n = n0 + n_w + (lane & 15);
        float v = acc[j];
        if (MODE == 0) {
            v += bias[n];
            v = fmaxf(v, 0.f);
            ushort_t h = f2bf(v);
            Ch[(size_t)m * N + n] = h;
            Cl[(size_t)m * N + n] = f2bf(v - bf2f(h));
        } else {
            if (bias) v += bias[n];
            Cf[(size_t)m * N + n] = v;
        }
    }
}

// 2D-tiled broadcast: block = (16 n-rows) x (16 m-rows) for one b.
// a1/a2 tiles in registers (statically indexed); each (i,j) writes one
// full contiguous 4KB row per block. Reads: 128KB per 1MB written.
__global__ __launch_bounds__(256) void bcast_relu(
    const f32x4* __restrict__ A1, const f32x4* __restrict__ A2,
    f32x4* __restrict__ out)
{
    const int t   = threadIdx.x;          // d in f32x4 units (0..255)
    const int m0  = blockIdx.x * 16;
    const int n0  = blockIdx.y * 16;
    const int b   = blockIdx.z;
    const int bn0 = (b << 8) + n0;        // b*N1 + n0

    f32x4 a1[16], a2[16];
    #pragma unroll
    for (int i = 0; i < 16; ++i)
        a1[i] = A1[(((size_t)(bn0 + i)) << 8) + t];
    #pragma unroll
    for (int j = 0; j < 16; ++j)
        a2[j] = A2[(((size_t)((b << 8) + m0 + j)) << 8) + t];

    f32x4* ob = out + (((size_t)bn0 << 8) + m0) * 256 + t;
    #pragma unroll
    for (int i = 0; i < 16; ++i) {
        #pragma unroll
        for (int j = 0; j < 16; ++j) {
            f32x4 v;
            v.x = fmaxf(a1[i].x + a2[j].x, 0.f);
            v.y = fmaxf(a1[i].y + a2[j].y, 0.f);
            v.z = fmaxf(a1[i].z + a2[j].z, 0.f);
            v.w = fmaxf(a1[i].w + a2[j].w, 0.f);
            __builtin_nontemporal_store(v, ob + (size_t)i * 65536 + j * 256);
        }
    }
}

extern "C" void kernel_launch(void* const* d_in, const int* in_sizes, int n_in,
                              void* d_out, int out_size, void* d_ws, size_t ws_size,
                              hipStream_t stream) {
    const float* span1  = (const float*)d_in[0];
    const float* span2  = (const float*)d_in[1];
    const float* W_red  = (const float*)d_in[2];
    const float* b_red  = (const float*)d_in[3];
    const float* W_repr = (const float*)d_in[4];
    const float* b_repr = (const float*)d_in[5];
    float* out = (float*)d_out;

    // workspace carve (~12 MB)
    float* A1 = (float*)d_ws;                       // 512*1024 f32
    float* A2 = A1 + 512 * 1024;
    ushort_t* p = (ushort_t*)(A2 + 512 * 1024);
    ushort_t* r1h = p;  p += 512 * 512;
    ushort_t* r1l = p;  p += 512 * 512;
    ushort_t* r2h = p;  p += 512 * 512;
    ushort_t* r2l = p;  p += 512 * 512;
    ushort_t* Wrth = p; p += 512 * 1024;            // W_red^T  [512][1024]
    ushort_t* Wrtl = p; p += 512 * 1024;
    ushort_t* Wpth = p; p += 1024 * 1024;           // W_repr^T [1024][1024]
    ushort_t* Wptl = p; p += 1024 * 1024;

    // transpose+split both weights, one launch
    prep_weights<<<dim3(24, 16), 256, 0, stream>>>(
        W_red, W_repr, Wrth, Wrtl, Wpth, Wptl);

    const int M = B_ * N1_;   // 512

    // stage 1: r{1,2} = relu(span{1,2} @ W_red + b_red) -> hi/lo bf16
    gemm_split<0><<<dim3(DRED_ / 64, M / 16, 2), 256, 0, stream>>>(
        span1, span2, nullptr, nullptr, nullptr, nullptr,
        Wrth, Wrtl, 0, 0, b_red, b_red,
        r1h, r1l, r2h, r2l, nullptr, nullptr,
        M, DRED_, DIN_, DIN_, DIN_);

    // stage 2: A1 = r1 @ Wa + b_repr ; A2 = r2 @ Wb
    gemm_split<1><<<dim3(DREP_ / 64, M / 16, 2), 256, 0, stream>>>(
        nullptr, nullptr, r1h, r1l, r2h, r2l,
        Wpth, Wptl, 0, DRED_, b_repr, nullptr,
        nullptr, nullptr, nullptr, nullptr, A1, A2,
        M, DREP_, DRED_, DRED_, 2 * DRED_);

    // stage 3: 2D-tiled broadcast + relu
    bcast_relu<<<dim3(N2_ / 16, N1_ / 16, B_), 256, 0, stream>>>(
        (const f32x4*)A1, (const f32x4*)A2, (f32x4*)out);
}

// Round 7
// 133.232 us; speedup vs baseline: 1.1541x; 1.0457x over previous
//
#include <hip/hip_runtime.h>

#define B_    2
#define N1_   256
#define N2_   256
#define DIN_  1024
#define DRED_ 512
#define DREP_ 1024

typedef unsigned short ushort_t;
typedef float f32x4 __attribute__((ext_vector_type(4)));
typedef short bf16x8 __attribute__((ext_vector_type(8)));

__device__ __forceinline__ ushort_t f2bf(float x) {
    unsigned u = __builtin_bit_cast(unsigned, x);
    unsigned r = (u + 0x7fffu + ((u >> 16) & 1u)) >> 16;   // RNE
    return (ushort_t)r;
}
__device__ __forceinline__ float bf2f(ushort_t h) {
    unsigned u = ((unsigned)h) << 16;
    return __builtin_bit_cast(float, u);
}
__device__ __forceinline__ void mfma16(f32x4& acc, bf16x8 a, bf16x8 b) {
    acc = __builtin_amdgcn_mfma_f32_16x16x32_bf16(a, b, acc, 0, 0, 0);
}

// One launch: transpose+split BOTH weights.
// blockIdx.x < 8  -> W_red  [1024][512]  -> Wrth/Wrtl [512][1024]
// else            -> W_repr [1024][1024] -> Wpth/Wptl [1024][1024]
__global__ __launch_bounds__(256) void prep_weights(
    const float* __restrict__ W_red, const float* __restrict__ W_repr,
    ushort_t* __restrict__ Wrth, ushort_t* __restrict__ Wrtl,
    ushort_t* __restrict__ Wpth, ushort_t* __restrict__ Wptl)
{
    int bx = blockIdx.x;
    const float* W; ushort_t *Th, *Tl; int N;
    if (bx < 8) { W = W_red;  Th = Wrth; Tl = Wrtl; N = DRED_; }
    else        { bx -= 8; W = W_repr; Th = Wpth; Tl = Wptl; N = DREP_; }
    const int K = 1024;

    __shared__ float T[64][65];
    const int tid = threadIdx.x;
    const int n0 = bx * 64;
    const int k0 = blockIdx.y * 64;
    #pragma unroll
    for (int p = 0; p < 4; ++p) {
        int r = (tid >> 4) + p * 16;
        int c = (tid & 15) * 4;
        float4 v = *reinterpret_cast<const float4*>(&W[(size_t)(k0 + r) * N + n0 + c]);
        T[r][c] = v.x; T[r][c + 1] = v.y; T[r][c + 2] = v.z; T[r][c + 3] = v.w;
    }
    __syncthreads();
    #pragma unroll
    for (int p = 0; p < 4; ++p) {
        int rn = (tid >> 4) + p * 16;
        int ck = (tid & 15) * 4;
        ushort_t hh[4], ll[4];
        #pragma unroll
        for (int j = 0; j < 4; ++j) {
            float v = T[ck + j][rn];
            hh[j] = f2bf(v);
            ll[j] = f2bf(v - bf2f(hh[j]));
        }
        *reinterpret_cast<ushort4*>(&Th[(size_t)(n0 + rn) * K + k0 + ck]) =
            ushort4{hh[0], hh[1], hh[2], hh[3]};
        *reinterpret_cast<ushort4*>(&Tl[(size_t)(n0 + rn) * K + k0 + ck]) =
            ushort4{ll[0], ll[1], ll[2], ll[3]};
    }
}

// Split-bf16 MFMA GEMM, dual tenant. Tile BM=16, BN=64, BK=64; 4 waves,
// each wave owns one 16x16 output fragment column (n_w = w*16).
// MODE 0: A fp32 (split in staging); C = relu(A@B+bias) -> hi/lo bf16.
// MODE 1: A hi/lo bf16; C = A@B (+bias if non-null) -> fp32.
// B pre-transposed/split [N][ldb]; bOff selects k-slice.
template<int MODE>
__global__ __launch_bounds__(256) void gemm_split(
    const float* __restrict__ Af0, const float* __restrict__ Af1,
    const ushort_t* __restrict__ Ah0, const ushort_t* __restrict__ Al0,
    const ushort_t* __restrict__ Ah1, const ushort_t* __restrict__ Al1,
    const ushort_t* __restrict__ Bh, const ushort_t* __restrict__ Bl,
    int bOff0, int bOff1,
    const float* __restrict__ bias0, const float* __restrict__ bias1,
    ushort_t* __restrict__ Ch0, ushort_t* __restrict__ Cl0,
    ushort_t* __restrict__ Ch1, ushort_t* __restrict__ Cl1,
    float* __restrict__ Cf0, float* __restrict__ Cf1,
    int M, int N, int K, int lda, int ldb)
{
    __shared__ ushort_t Ash[16][72];
    __shared__ ushort_t Asl[16][72];
    __shared__ ushort_t Bsh[64][72];
    __shared__ ushort_t Bsl[64][72];

    const int tid = threadIdx.x;
    const int z  = blockIdx.z;
    const int m0 = blockIdx.y * 16;
    const int n0 = blockIdx.x * 64;

    const float*    Af   = z ? Af1 : Af0;
    const ushort_t* Ah   = z ? Ah1 : Ah0;
    const ushort_t* Al   = z ? Al1 : Al0;
    const int       bOff = z ? bOff1 : bOff0;
    const float*    bias = z ? bias1 : bias0;

    const int lane = tid & 63;
    const int w    = tid >> 6;
    const int n_w  = w * 16;
    const int lrow = lane & 15;
    const int lkg  = (lane >> 4) * 8;

    const int ar  = tid >> 4;          // 0..15
    const int ac4 = (tid & 15) * 4;    // 4-elem col group

    f32x4 acc = {};

    for (int k0 = 0; k0 < K; k0 += 64) {
        // ---- stage A (16 x 64) ----
        if (MODE == 0) {
            float4 v = *reinterpret_cast<const float4*>(&Af[(size_t)(m0 + ar) * lda + k0 + ac4]);
            float vv[4] = {v.x, v.y, v.z, v.w};
            ushort_t hh[4], ll[4];
            #pragma unroll
            for (int j = 0; j < 4; ++j) {
                hh[j] = f2bf(vv[j]);
                ll[j] = f2bf(vv[j] - bf2f(hh[j]));
            }
            *reinterpret_cast<ushort4*>(&Ash[ar][ac4]) = ushort4{hh[0], hh[1], hh[2], hh[3]};
            *reinterpret_cast<ushort4*>(&Asl[ar][ac4]) = ushort4{ll[0], ll[1], ll[2], ll[3]};
        } else {
            *reinterpret_cast<ushort4*>(&Ash[ar][ac4]) =
                *reinterpret_cast<const ushort4*>(&Ah[(size_t)(m0 + ar) * lda + k0 + ac4]);
            *reinterpret_cast<ushort4*>(&Asl[ar][ac4]) =
                *reinterpret_cast<const ushort4*>(&Al[(size_t)(m0 + ar) * lda + k0 + ac4]);
        }
        // ---- stage B (64 n-rows x 64 k), pre-transposed/split ----
        #pragma unroll
        for (int p = 0; p < 2; ++p) {
            int r = (tid >> 3) + p * 32;
            int c = (tid & 7) * 8;
            *reinterpret_cast<uint4*>(&Bsh[r][c]) =
                *reinterpret_cast<const uint4*>(&Bh[(size_t)(n0 + r) * ldb + bOff + k0 + c]);
            *reinterpret_cast<uint4*>(&Bsl[r][c]) =
                *reinterpret_cast<const uint4*>(&Bl[(size_t)(n0 + r) * ldb + bOff + k0 + c]);
        }
        __syncthreads();

        #pragma unroll
        for (int s = 0; s < 2; ++s) {
            const int kk = s * 32 + lkg;
            bf16x8 ah = *reinterpret_cast<const bf16x8*>(&Ash[lrow][kk]);
            bf16x8 al = *reinterpret_cast<const bf16x8*>(&Asl[lrow][kk]);
            bf16x8 bh = *reinterpret_cast<const bf16x8*>(&Bsh[n_w + lrow][kk]);
            bf16x8 bl = *reinterpret_cast<const bf16x8*>(&Bsl[n_w + lrow][kk]);
            mfma16(acc, ah, bh);
            mfma16(acc, ah, bl);
            mfma16(acc, al, bh);
        }
        __syncthreads();
    }

    ushort_t* Ch = z ? Ch1 : Ch0;
    ushort_t* Cl = z ? Cl1 : Cl0;
    float*    Cf = z ? Cf1 : Cf0;

    #pragma unroll
    for (int j = 0; j < 4; ++j) {
        const int m = m0 + (lane >> 4) * 4 + j;
        const int n = n0 + n_w + (lane & 15);
        float v = acc[j];
        if (MODE == 0) {
            v += bias[n];
            v = fmaxf(v, 0.f);
            ushort_t h = f2bf(v);
            Ch[(size_t)m * N + n] = h;
            Cl[(size_t)m * N + n] = f2bf(v - bf2f(h));
        } else {
            if (bias) v += bias[n];
            Cf[(size_t)m * N + n] = v;
        }
    }
}

// Fill-style streaming broadcast: block = (b, n, m-half).
// Each block writes a CONTIGUOUS 512KB span out[b][n][m0:m0+128][:]
// in ascending order. a1 row held in registers (one f32x4/lane);
// a2 rows stream from L2, 8 ahead.
__global__ __launch_bounds__(256) void bcast_relu(
    const f32x4* __restrict__ A1, const f32x4* __restrict__ A2,
    f32x4* __restrict__ out)
{
    const int t    = threadIdx.x;         // d-slice (0..255)
    const int bid  = blockIdx.x;          // 0..1023
    const int bn   = bid >> 1;            // b*N1 + n
    const int half = bid & 1;
    const int b    = bn >> 8;
    const int m0   = half << 7;           // 0 or 128

    const f32x4 a1 = A1[((size_t)bn << 8) + t];
    const f32x4* a2p = A2 + (((size_t)(b << 8) + m0) << 8) + t;
    f32x4* op = out + (((size_t)(bn << 8) + m0) << 8) + t;

    for (int m = 0; m < 128; m += 8) {
        f32x4 r[8];
        #pragma unroll
        for (int j = 0; j < 8; ++j)
            r[j] = a2p[(size_t)(m + j) << 8];
        #pragma unroll
        for (int j = 0; j < 8; ++j) {
            f32x4 v;
            v.x = fmaxf(a1.x + r[j].x, 0.f);
            v.y = fmaxf(a1.y + r[j].y, 0.f);
            v.z = fmaxf(a1.z + r[j].z, 0.f);
            v.w = fmaxf(a1.w + r[j].w, 0.f);
            op[(size_t)(m + j) << 8] = v;
        }
    }
}

extern "C" void kernel_launch(void* const* d_in, const int* in_sizes, int n_in,
                              void* d_out, int out_size, void* d_ws, size_t ws_size,
                              hipStream_t stream) {
    const float* span1  = (const float*)d_in[0];
    const float* span2  = (const float*)d_in[1];
    const float* W_red  = (const float*)d_in[2];
    const float* b_red  = (const float*)d_in[3];
    const float* W_repr = (const float*)d_in[4];
    const float* b_repr = (const float*)d_in[5];
    float* out = (float*)d_out;

    // workspace carve (~12 MB)
    float* A1 = (float*)d_ws;                       // 512*1024 f32
    float* A2 = A1 + 512 * 1024;
    ushort_t* p = (ushort_t*)(A2 + 512 * 1024);
    ushort_t* r1h = p;  p += 512 * 512;
    ushort_t* r1l = p;  p += 512 * 512;
    ushort_t* r2h = p;  p += 512 * 512;
    ushort_t* r2l = p;  p += 512 * 512;
    ushort_t* Wrth = p; p += 512 * 1024;            // W_red^T  [512][1024]
    ushort_t* Wrtl = p; p += 512 * 1024;
    ushort_t* Wpth = p; p += 1024 * 1024;           // W_repr^T [1024][1024]
    ushort_t* Wptl = p; p += 1024 * 1024;

    // transpose+split both weights, one launch
    prep_weights<<<dim3(24, 16), 256, 0, stream>>>(
        W_red, W_repr, Wrth, Wrtl, Wpth, Wptl);

    const int M = B_ * N1_;   // 512

    // stage 1: r{1,2} = relu(span{1,2} @ W_red + b_red) -> hi/lo bf16
    gemm_split<0><<<dim3(DRED_ / 64, M / 16, 2), 256, 0, stream>>>(
        span1, span2, nullptr, nullptr, nullptr, nullptr,
        Wrth, Wrtl, 0, 0, b_red, b_red,
        r1h, r1l, r2h, r2l, nullptr, nullptr,
        M, DRED_, DIN_, DIN_, DIN_);

    // stage 2: A1 = r1 @ Wa + b_repr ; A2 = r2 @ Wb
    gemm_split<1><<<dim3(DREP_ / 64, M / 16, 2), 256, 0, stream>>>(
        nullptr, nullptr, r1h, r1l, r2h, r2l,
        Wpth, Wptl, 0, DRED_, b_repr, nullptr,
        nullptr, nullptr, nullptr, nullptr, A1, A2,
        M, DREP_, DRED_, DRED_, 2 * DRED_);

    // stage 3: fill-style streaming broadcast + relu
    bcast_relu<<<dim3(1024), 256, 0, stream>>>(
        (const f32x4*)A1, (const f32x4*)A2, (f32x4*)out);
}